// Round 16
// baseline (301.600 us; speedup 1.0000x reference)
//
#include <hip/hip_runtime.h>
#include <hip/hip_fp16.h>
#include <cstdint>
#include <cstddef>

// ---------------------------------------------------------------------------
// 2-layer GCN (PyG GCNConv semantics) on MI355X.
// Round 16: round-15 pipeline (best: 298.6us) +
//  (1) k_bktscan folded into k_csr3 (per-block base reduction),
//  (2) k_csr3 stages bucket window in LDS (single global read),
//  (3) gathers 32-edge-deep unroll (MLP probe below the 3.3TB/s fill ceiling).
// ---------------------------------------------------------------------------

#define BSHIFT 8          // 256 nodes per bucket
#define CAP    12288      // part[] capacity per bucket (mean 8184, sd ~90)

typedef _Float16 half8 __attribute__((ext_vector_type(8)));
typedef float f32x4 __attribute__((ext_vector_type(4)));

__global__ __launch_bounds__(256) void k_binit(int* __restrict__ bktcur, int nbkt) {
  int b = blockIdx.x * 256 + threadIdx.x;
  if (b < nbkt) bktcur[b] = b * CAP;
}

// Partition with in-LDS reorder: hist -> local scan -> global reservation ->
// LDS scatter -> linear write-out (contiguous per-bucket runs).
__global__ __launch_bounds__(256) void k_part3(const int* __restrict__ src,
                                               const int* __restrict__ dst,
                                               int* __restrict__ bktcur,
                                               int* __restrict__ part, int E,
                                               int nbkt) {
  __shared__ int vals[4096];
  __shared__ unsigned short bid[4096];
  __shared__ int hist[512];   // counts -> local running cursor
  __shared__ int lbase[512];  // local exclusive base
  __shared__ int gbase[512];  // global reserved base
  const int tid = threadIdx.x;
  const int e0 = blockIdx.x * 4096;
  const int ecnt = min(4096, E - e0);
  for (int b = tid; b < nbkt; b += 256) hist[b] = 0;
  __syncthreads();

  int eb[16], ev[16];
#pragma unroll
  for (int j = 0; j < 16; ++j) {
    const int e = e0 + j * 256 + tid;
    eb[j] = -1;
    ev[j] = 0;
    if (e < E) {
      const int d = dst[e];
      eb[j] = d >> BSHIFT;
      ev[j] = (src[e] << BSHIFT) | (d & ((1 << BSHIFT) - 1));
      atomicAdd(&hist[eb[j]], 1);
    }
  }
  __syncthreads();

  if (tid == 0) {  // serial exclusive scan over nbkt (<1us, overlapped)
    int run = 0;
    for (int b = 0; b < nbkt; ++b) {
      const int c = hist[b];
      lbase[b] = run;
      run += c;
    }
  }
  __syncthreads();
  for (int b = tid; b < nbkt; b += 256) {
    const int c = hist[b];
    gbase[b] = c ? atomicAdd(&bktcur[b], c) : 0;
    hist[b] = lbase[b];  // becomes local cursor
  }
  __syncthreads();

#pragma unroll
  for (int j = 0; j < 16; ++j) {
    if (eb[j] >= 0) {
      const int lpos = atomicAdd(&hist[eb[j]], 1);
      vals[lpos] = ev[j];
      bid[lpos] = (unsigned short)eb[j];
    }
  }
  __syncthreads();

  for (int s = tid; s < ecnt; s += 256) {
    const int b = bid[s];
    const int gpos = gbase[b] + (s - lbase[b]);
    if (gpos < (b + 1) * CAP)  // statistical impossibility guard
      part[gpos] = vals[s];
  }
}

// Per bucket: compute own base (reduce bktcur[0..b)), stage window in LDS,
// count -> scan -> offsets + dinv, then compact scatter into final CSR slots.
__global__ __launch_bounds__(256) void k_csr3(const int* __restrict__ part,
                                              const int* __restrict__ bktcur,
                                              int* __restrict__ offsets,
                                              int* __restrict__ csr_src,
                                              float* __restrict__ dinv, int n,
                                              int E) {
  __shared__ int win[CAP];  // 48KB window stage
  __shared__ int cnt[256];
  __shared__ int ts[256];
  const int b = blockIdx.x;
  const int node0 = b << BSHIFT;
  const int nn = min(256, n - node0);
  const int t = threadIdx.x;

  // bucket base = sum_{j<b} (bktcur[j] - j*CAP)
  int partial = 0;
  for (int j = t; j < b; j += 256) partial += bktcur[j] - j * CAP;
  ts[t] = partial;
  __syncthreads();
  for (int off = 128; off > 0; off >>= 1) {
    if (t < off) ts[t] += ts[t + off];
    __syncthreads();
  }
  const int w0 = ts[0];
  __syncthreads();

  const int w0p = b * CAP;
  const int wcnt = min(bktcur[b], w0p + CAP) - w0p;
  for (int e = t; e < wcnt; e += 256) win[e] = part[w0p + e];
  cnt[t] = 0;
  __syncthreads();
  for (int e = t; e < wcnt; e += 256)
    atomicAdd(&cnt[win[e] & ((1 << BSHIFT) - 1)], 1);
  __syncthreads();
  const int c = cnt[t];
  ts[t] = c;
  __syncthreads();
  for (int off = 1; off < 256; off <<= 1) {
    const int u = (t >= off) ? ts[t - off] : 0;
    __syncthreads();
    ts[t] += u;
    __syncthreads();
  }
  const int excl = ts[t] - c;
  if (t < nn) {
    offsets[node0 + t] = w0 + excl;
    dinv[node0 + t] = rsqrtf((float)c + 1.0f);
  }
  if (b == 0 && t == 0) offsets[n] = E;
  cnt[t] = w0 + excl;  // becomes cursor
  __syncthreads();
  for (int e = t; e < wcnt; e += 256) {
    const int p = win[e];
    const int pos = atomicAdd(&cnt[p & ((1 << BSHIFT) - 1)], 1);
    csr_src[pos] = p >> BSHIFT;
  }
}

// ---------------------------------------------------------------------------
// MFMA fp16 GEMM: Hout[N,COLS](fp16) = (A[N,128] @ W[128,COLS]) * dinv[row].
// ---------------------------------------------------------------------------
template <typename TA, int COLS>
__global__ __launch_bounds__(256) void k_gemm_mfma(const TA* __restrict__ A,
                                                   const float* __restrict__ W,
                                                   const float* __restrict__ dinv,
                                                   __half* __restrict__ Hout,
                                                   int N, int ntiles) {
  constexpr int RW = (COLS == 128) ? 2 : 4;  // row-waves per tile
  constexpr int RPT = RW * 16;               // rows per tile
  __shared__ _Float16 Wt[128 * COLS];
  __shared__ _Float16 Lb[4][16][72];
  const int tid = threadIdx.x;
  const int w = tid >> 6;
  const int l = tid & 63;

  for (int f = tid; f < (128 * COLS) / 4; f += 256) {
    const int k = f / (COLS / 4);
    const int c4 = (f % (COLS / 4)) * 4;
    const float4 wv = *reinterpret_cast<const float4*>(W + (size_t)k * COLS + c4);
#pragma unroll
    for (int j = 0; j < 4; ++j) {
      const int cc = c4 + j;
      Wt[(cc * 128 + k) ^ ((cc & 7) << 3)] = (_Float16)(&wv.x)[j];
    }
  }
  __syncthreads();

  const int colw = (COLS == 128) ? (w >> 1) * 64 : 0;
  const int rw = (COLS == 128) ? (w & 1) : w;
  const int koff = (l >> 4) * 8;

  half8 bf[4][4];
#pragma unroll
  for (int t = 0; t < 4; ++t)
#pragma unroll
    for (int s = 0; s < 4; ++s) {
      const int cc = colw + 16 * t + (l & 15);
      const int kk = 32 * s + koff;
      bf[t][s] =
          *reinterpret_cast<const half8*>(&Wt[(cc * 128 + kk) ^ ((cc & 7) << 3)]);
    }

  for (int tile = blockIdx.x; tile < ntiles; tile += gridDim.x) {
    const int row = tile * RPT + rw * 16 + (l & 15);
    const int rowc = (row < N) ? row : (N - 1);
    f32x4 acc[4];
#pragma unroll
    for (int t = 0; t < 4; ++t) acc[t] = (f32x4){0.f, 0.f, 0.f, 0.f};

#pragma unroll
    for (int s = 0; s < 4; ++s) {
      half8 af;
      if constexpr (sizeof(TA) == 4) {
        const float* ap = (const float*)A + (size_t)rowc * 128 + 32 * s + koff;
        const float4 a0 = *reinterpret_cast<const float4*>(ap);
        const float4 a1 = *reinterpret_cast<const float4*>(ap + 4);
#pragma unroll
        for (int j = 0; j < 4; ++j) {
          af[j] = (_Float16)(&a0.x)[j];
          af[4 + j] = (_Float16)(&a1.x)[j];
        }
      } else {
        af = *reinterpret_cast<const half8*>((const __half*)A +
                                             (size_t)rowc * 128 + 32 * s + koff);
      }
#pragma unroll
      for (int t = 0; t < 4; ++t)
        acc[t] = __builtin_amdgcn_mfma_f32_16x16x32_f16(af, bf[t][s], acc[t],
                                                        0, 0, 0);
    }

    const int rbase = tile * RPT + rw * 16 + (l >> 4) * 4;
    float dr[4];
#pragma unroll
    for (int r = 0; r < 4; ++r) {
      const int rr = rbase + r;
      dr[r] = (rr < N) ? dinv[rr] : 0.f;
    }

#pragma unroll
    for (int t = 0; t < 4; ++t)
#pragma unroll
      for (int r = 0; r < 4; ++r)
        Lb[w][(l >> 4) * 4 + r][16 * t + (l & 15)] = (_Float16)(acc[t][r] * dr[r]);
    const int orow = tile * RPT + rw * 16 + (l & 15);
    if (orow < N) {
      const int ch = (l >> 4) * 16;
      const half8 v0 = *reinterpret_cast<const half8*>(&Lb[w][l & 15][ch]);
      const half8 v1 = *reinterpret_cast<const half8*>(&Lb[w][l & 15][ch + 8]);
      __half* hp = Hout + (size_t)orow * COLS + colw + ch;
      *reinterpret_cast<half8*>(hp) = v0;
      *reinterpret_cast<half8*>(hp + 8) = v1;
    }
  }
}

// ---------------------------------------------------------------------------
// Wide CSR gather over pre-scaled H (Hs = h*dinv, fp16), fp32 accumulate.
//   out[i] = relu( dinv[i] * (sum Hs[s] + Hs[i]) + bias )
// One wave per node; 8 edge slots x 8 channel lanes; 32/16-deep unrolled
// main loops (no masking), masked 8-tail. No per-edge dinv load.
// ---------------------------------------------------------------------------
__global__ __launch_bounds__(256) void k_gather128(
    const __half* __restrict__ H, const int* __restrict__ offsets,
    const int* __restrict__ csr_src, const float* __restrict__ dinv,
    const float* __restrict__ bias, __half* __restrict__ out, int N) {
  const int lane = threadIdx.x & 63;
  const int g = lane >> 3;  // 0..7 edge slot
  const int sl = lane & 7;  // 0..7 channel block (16 ch)
  int w = (blockIdx.x * 256 + threadIdx.x) >> 6;
  const int nw = (gridDim.x * 256) >> 6;
  for (int i = w; i < N; i += nw) {
    const int beg = offsets[i];
    const int end = offsets[i + 1];
    float acc[16];
    {
      const float vf = (g == 0) ? 1.f : 0.f;
      const float4 ha = *reinterpret_cast<const float4*>(H + (size_t)i * 128 + sl * 16);
      const float4 hb = *reinterpret_cast<const float4*>(H + (size_t)i * 128 + sl * 16 + 8);
      const __half2* pa = reinterpret_cast<const __half2*>(&ha);
      const __half2* pb = reinterpret_cast<const __half2*>(&hb);
#pragma unroll
      for (int q = 0; q < 4; ++q) {
        const float2 fa = __half22float2(pa[q]);
        const float2 fb = __half22float2(pb[q]);
        acc[q * 2] = vf * fa.x;
        acc[q * 2 + 1] = vf * fa.y;
        acc[8 + q * 2] = vf * fb.x;
        acc[8 + q * 2 + 1] = vf * fb.y;
      }
    }
    int base = beg;
    for (; base + 32 <= end; base += 32) {  // 32-deep: 4 edge groups in flight
      int s[4];
#pragma unroll
      for (int u = 0; u < 4; ++u)
        s[u] = __builtin_nontemporal_load(csr_src + base + u * 8 + g);
      float4 hv[8];
#pragma unroll
      for (int u = 0; u < 4; ++u) {
        hv[u * 2] = *reinterpret_cast<const float4*>(H + (size_t)s[u] * 128 + sl * 16);
        hv[u * 2 + 1] =
            *reinterpret_cast<const float4*>(H + (size_t)s[u] * 128 + sl * 16 + 8);
      }
#pragma unroll
      for (int u = 0; u < 4; ++u) {
        const __half2* pa = reinterpret_cast<const __half2*>(&hv[u * 2]);
        const __half2* pb = reinterpret_cast<const __half2*>(&hv[u * 2 + 1]);
#pragma unroll
        for (int q = 0; q < 4; ++q) {
          const float2 fa = __half22float2(pa[q]);
          const float2 fb = __half22float2(pb[q]);
          acc[q * 2] += fa.x;
          acc[q * 2 + 1] += fa.y;
          acc[8 + q * 2] += fb.x;
          acc[8 + q * 2 + 1] += fb.y;
        }
      }
    }
    for (; base + 16 <= end; base += 16) {  // 16-deep
      const int s0 = __builtin_nontemporal_load(csr_src + base + g);
      const int s1 = __builtin_nontemporal_load(csr_src + base + 8 + g);
      const float4 h0a = *reinterpret_cast<const float4*>(H + (size_t)s0 * 128 + sl * 16);
      const float4 h0b = *reinterpret_cast<const float4*>(H + (size_t)s0 * 128 + sl * 16 + 8);
      const float4 h1a = *reinterpret_cast<const float4*>(H + (size_t)s1 * 128 + sl * 16);
      const float4 h1b = *reinterpret_cast<const float4*>(H + (size_t)s1 * 128 + sl * 16 + 8);
      const __half2* p0a = reinterpret_cast<const __half2*>(&h0a);
      const __half2* p0b = reinterpret_cast<const __half2*>(&h0b);
      const __half2* p1a = reinterpret_cast<const __half2*>(&h1a);
      const __half2* p1b = reinterpret_cast<const __half2*>(&h1b);
#pragma unroll
      for (int q = 0; q < 4; ++q) {
        const float2 f0a = __half22float2(p0a[q]);
        const float2 f0b = __half22float2(p0b[q]);
        const float2 f1a = __half22float2(p1a[q]);
        const float2 f1b = __half22float2(p1b[q]);
        acc[q * 2] += f0a.x + f1a.x;
        acc[q * 2 + 1] += f0a.y + f1a.y;
        acc[8 + q * 2] += f0b.x + f1b.x;
        acc[8 + q * 2 + 1] += f0b.y + f1b.y;
      }
    }
    for (; base < end; base += 8) {  // masked tail
      const int e = base + g;
      const bool v = e < end;
      const int s = v ? __builtin_nontemporal_load(csr_src + e) : i;
      const float vf = v ? 1.f : 0.f;
      const float4 ha = *reinterpret_cast<const float4*>(H + (size_t)s * 128 + sl * 16);
      const float4 hb = *reinterpret_cast<const float4*>(H + (size_t)s * 128 + sl * 16 + 8);
      const __half2* pa = reinterpret_cast<const __half2*>(&ha);
      const __half2* pb = reinterpret_cast<const __half2*>(&hb);
#pragma unroll
      for (int q = 0; q < 4; ++q) {
        const float2 fa = __half22float2(pa[q]);
        const float2 fb = __half22float2(pb[q]);
        acc[q * 2] = fmaf(vf, fa.x, acc[q * 2]);
        acc[q * 2 + 1] = fmaf(vf, fa.y, acc[q * 2 + 1]);
        acc[8 + q * 2] = fmaf(vf, fb.x, acc[8 + q * 2]);
        acc[8 + q * 2 + 1] = fmaf(vf, fb.y, acc[8 + q * 2 + 1]);
      }
    }
#pragma unroll
    for (int j = 0; j < 16; ++j) {
      float a = acc[j];
      a += __shfl_xor(a, 8);
      a += __shfl_xor(a, 16);
      a += __shfl_xor(a, 32);
      acc[j] = a;
    }
    if (g == 0) {
      const float di = dinv[i];
      __half2 ov[8];
#pragma unroll
      for (int q = 0; q < 8; ++q) {
        const float2 bv = *reinterpret_cast<const float2*>(bias + sl * 16 + q * 2);
        ov[q] = __floats2half2_rn(fmaxf(fmaf(di, acc[q * 2], bv.x), 0.f),
                                  fmaxf(fmaf(di, acc[q * 2 + 1], bv.y), 0.f));
      }
      __half* op = out + (size_t)i * 128 + sl * 16;
      *reinterpret_cast<float4*>(op) = *reinterpret_cast<const float4*>(&ov[0]);
      *reinterpret_cast<float4*>(op + 8) = *reinterpret_cast<const float4*>(&ov[4]);
    }
  }
}

__global__ __launch_bounds__(256) void k_gather64(
    const __half* __restrict__ H, const int* __restrict__ offsets,
    const int* __restrict__ csr_src, const float* __restrict__ dinv,
    const float* __restrict__ bias, float* __restrict__ out, int N) {
  const int lane = threadIdx.x & 63;
  const int g = lane >> 3;  // 0..7 edge slot
  const int sl = lane & 7;  // 0..7 channel block (8 ch)
  int w = (blockIdx.x * 256 + threadIdx.x) >> 6;
  const int nw = (gridDim.x * 256) >> 6;
  for (int i = w; i < N; i += nw) {
    const int beg = offsets[i];
    const int end = offsets[i + 1];
    float acc[8];
    {
      const float vf = (g == 0) ? 1.f : 0.f;
      const float4 ha = *reinterpret_cast<const float4*>(H + (size_t)i * 64 + sl * 8);
      const __half2* pa = reinterpret_cast<const __half2*>(&ha);
#pragma unroll
      for (int q = 0; q < 4; ++q) {
        const float2 fa = __half22float2(pa[q]);
        acc[q * 2] = vf * fa.x;
        acc[q * 2 + 1] = vf * fa.y;
      }
    }
    int base = beg;
    for (; base + 32 <= end; base += 32) {  // 32-deep
      int s[4];
#pragma unroll
      for (int u = 0; u < 4; ++u)
        s[u] = __builtin_nontemporal_load(csr_src + base + u * 8 + g);
      float4 hv[4];
#pragma unroll
      for (int u = 0; u < 4; ++u)
        hv[u] = *reinterpret_cast<const float4*>(H + (size_t)s[u] * 64 + sl * 8);
#pragma unroll
      for (int u = 0; u < 4; ++u) {
        const __half2* pa = reinterpret_cast<const __half2*>(&hv[u]);
#pragma unroll
        for (int q = 0; q < 4; ++q) {
          const float2 fa = __half22float2(pa[q]);
          acc[q * 2] += fa.x;
          acc[q * 2 + 1] += fa.y;
        }
      }
    }
    for (; base + 16 <= end; base += 16) {
      const int s0 = __builtin_nontemporal_load(csr_src + base + g);
      const int s1 = __builtin_nontemporal_load(csr_src + base + 8 + g);
      const float4 h0 = *reinterpret_cast<const float4*>(H + (size_t)s0 * 64 + sl * 8);
      const float4 h1 = *reinterpret_cast<const float4*>(H + (size_t)s1 * 64 + sl * 8);
      const __half2* p0 = reinterpret_cast<const __half2*>(&h0);
      const __half2* p1 = reinterpret_cast<const __half2*>(&h1);
#pragma unroll
      for (int q = 0; q < 4; ++q) {
        const float2 f0 = __half22float2(p0[q]);
        const float2 f1 = __half22float2(p1[q]);
        acc[q * 2] += f0.x + f1.x;
        acc[q * 2 + 1] += f0.y + f1.y;
      }
    }
    for (; base < end; base += 8) {
      const int e = base + g;
      const bool v = e < end;
      const int s = v ? __builtin_nontemporal_load(csr_src + e) : i;
      const float vf = v ? 1.f : 0.f;
      const float4 ha = *reinterpret_cast<const float4*>(H + (size_t)s * 64 + sl * 8);
      const __half2* pa = reinterpret_cast<const __half2*>(&ha);
#pragma unroll
      for (int q = 0; q < 4; ++q) {
        const float2 fa = __half22float2(pa[q]);
        acc[q * 2] = fmaf(vf, fa.x, acc[q * 2]);
        acc[q * 2 + 1] = fmaf(vf, fa.y, acc[q * 2 + 1]);
      }
    }
#pragma unroll
    for (int j = 0; j < 8; ++j) {
      float a = acc[j];
      a += __shfl_xor(a, 8);
      a += __shfl_xor(a, 16);
      a += __shfl_xor(a, 32);
      acc[j] = a;
    }
    if (g == 0) {
      const float di = dinv[i];
      float* op = out + (size_t)i * 64 + sl * 8;
      const float4 b0 = *reinterpret_cast<const float4*>(bias + sl * 8);
      const float4 b1 = *reinterpret_cast<const float4*>(bias + sl * 8 + 4);
      float4 o;
      o.x = fmaxf(fmaf(di, acc[0], b0.x), 0.f);
      o.y = fmaxf(fmaf(di, acc[1], b0.y), 0.f);
      o.z = fmaxf(fmaf(di, acc[2], b0.z), 0.f);
      o.w = fmaxf(fmaf(di, acc[3], b0.w), 0.f);
      *reinterpret_cast<float4*>(op) = o;
      o.x = fmaxf(fmaf(di, acc[4], b1.x), 0.f);
      o.y = fmaxf(fmaf(di, acc[5], b1.y), 0.f);
      o.z = fmaxf(fmaf(di, acc[6], b1.z), 0.f);
      o.w = fmaxf(fmaf(di, acc[7], b1.w), 0.f);
      *reinterpret_cast<float4*>(op + 4) = o;
    }
  }
}

extern "C" void kernel_launch(void* const* d_in, const int* in_sizes, int n_in,
                              void* d_out, int out_size, void* d_ws,
                              size_t ws_size, hipStream_t stream) {
  const float* x  = (const float*)d_in[0];
  const int*   ei = (const int*)d_in[1];
  const float* W1 = (const float*)d_in[2];
  const float* b1 = (const float*)d_in[3];
  const float* W2 = (const float*)d_in[4];
  const float* b2 = (const float*)d_in[5];

  const int IN  = 128;
  const int n   = in_sizes[0] / IN;   // 100000
  const int E   = in_sizes[1] / 2;    // 3200000
  const int* srcv = ei;
  const int* dstv = ei + E;
  float* out = (float*)d_out;

  const int NBKT = (n + 255) >> BSHIFT;    // buckets (391)
  const int NCHK = (E + 4095) / 4096;      // partition chunks (782)
  const int NT1  = (n + 31) / 32;          // layer-1 tiles (3125)
  const int NT2  = (n + 63) / 64;          // layer-2 tiles (1563)

  // Workspace (~65 MB): part[] aliases hprime (dead until gather128 writes it).
  char* p = (char*)d_ws;
  auto take = [&](size_t bytes) {
    char* r = p;
    p += (bytes + 255) & ~(size_t)255;
    return r;
  };
  float*  dinv    = (float*)take((size_t)n * 4);
  int*    offsets = (int*)take((size_t)(n + 1) * 4);
  int*    bktcur  = (int*)take(512 * 4);
  int*    csr_src = (int*)take((size_t)E * 4);            // 12.8 MB
  __half* H16     = (__half*)take((size_t)n * 128 * 2);   // 25.6 MB (H1s; later H2s)
  __half* hprime  = (__half*)take((size_t)n * 128 * 2);   // 25.6 MB (h' fp16)
  int*    part    = (int*)hprime;                          // 19.2 MB alias

  // --- single-pass CSR build (3 kernels) ---
  k_binit<<<(NBKT + 255) / 256, 256, 0, stream>>>(bktcur, NBKT);
  k_part3<<<NCHK, 256, 0, stream>>>(srcv, dstv, bktcur, part, E, NBKT);
  k_csr3<<<NBKT, 256, 0, stream>>>(part, bktcur, offsets, csr_src, dinv, n, E);

  // --- layer 1: H1s = (x@W1)*dinv (fp16) ; gather -> h' (fp16) ---
  k_gemm_mfma<float, 128><<<512, 256, 0, stream>>>(x, W1, dinv, H16, n, NT1);
  k_gather128<<<25000, 256, 0, stream>>>(H16, offsets, csr_src, dinv, b1,
                                         hprime, n);

  // --- layer 2: H2s = (h'@W2)*dinv (fp16) ; gather -> d_out ---
  k_gemm_mfma<__half, 64><<<512, 256, 0, stream>>>(hprime, W2, dinv, H16, n, NT2);
  k_gather64<<<25000, 256, 0, stream>>>(H16, offsets, csr_src, dinv, b2,
                                        out, n);
}

// Round 19
// 288.935 us; speedup vs baseline: 1.0438x; 1.0438x over previous
//
#include <hip/hip_runtime.h>
#include <hip/hip_fp16.h>
#include <cstdint>
#include <cstddef>

// ---------------------------------------------------------------------------
// 2-layer GCN (PyG GCNConv semantics) on MI355X.
// Round 17 (2nd resubmit after repeated infra failures): best-of
// recombination — round-16 CSR build (k_part3 + k_csr3, no bktscan) +
// round-15 gathers (16-deep unroll, VGPR 44; the 32-deep variant cost
// occupancy and regressed).
// ---------------------------------------------------------------------------

#define BSHIFT 8          // 256 nodes per bucket
#define CAP    12288      // part[] capacity per bucket (mean 8184, sd ~90)

typedef _Float16 half8 __attribute__((ext_vector_type(8)));
typedef float f32x4 __attribute__((ext_vector_type(4)));

__global__ __launch_bounds__(256) void k_binit(int* __restrict__ bktcur, int nbkt) {
  int b = blockIdx.x * 256 + threadIdx.x;
  if (b < nbkt) bktcur[b] = b * CAP;
}

// Partition with in-LDS reorder: hist -> local scan -> global reservation ->
// LDS scatter -> linear write-out (contiguous per-bucket runs).
__global__ __launch_bounds__(256) void k_part3(const int* __restrict__ src,
                                               const int* __restrict__ dst,
                                               int* __restrict__ bktcur,
                                               int* __restrict__ part, int E,
                                               int nbkt) {
  __shared__ int vals[4096];
  __shared__ unsigned short bid[4096];
  __shared__ int hist[512];   // counts -> local running cursor
  __shared__ int lbase[512];  // local exclusive base
  __shared__ int gbase[512];  // global reserved base
  const int tid = threadIdx.x;
  const int e0 = blockIdx.x * 4096;
  const int ecnt = min(4096, E - e0);
  for (int b = tid; b < nbkt; b += 256) hist[b] = 0;
  __syncthreads();

  int eb[16], ev[16];
#pragma unroll
  for (int j = 0; j < 16; ++j) {
    const int e = e0 + j * 256 + tid;
    eb[j] = -1;
    ev[j] = 0;
    if (e < E) {
      const int d = dst[e];
      eb[j] = d >> BSHIFT;
      ev[j] = (src[e] << BSHIFT) | (d & ((1 << BSHIFT) - 1));
      atomicAdd(&hist[eb[j]], 1);
    }
  }
  __syncthreads();

  if (tid == 0) {  // serial exclusive scan over nbkt (<1us, overlapped)
    int run = 0;
    for (int b = 0; b < nbkt; ++b) {
      const int c = hist[b];
      lbase[b] = run;
      run += c;
    }
  }
  __syncthreads();
  for (int b = tid; b < nbkt; b += 256) {
    const int c = hist[b];
    gbase[b] = c ? atomicAdd(&bktcur[b], c) : 0;
    hist[b] = lbase[b];  // becomes local cursor
  }
  __syncthreads();

#pragma unroll
  for (int j = 0; j < 16; ++j) {
    if (eb[j] >= 0) {
      const int lpos = atomicAdd(&hist[eb[j]], 1);
      vals[lpos] = ev[j];
      bid[lpos] = (unsigned short)eb[j];
    }
  }
  __syncthreads();

  for (int s = tid; s < ecnt; s += 256) {
    const int b = bid[s];
    const int gpos = gbase[b] + (s - lbase[b]);
    if (gpos < (b + 1) * CAP)  // statistical impossibility guard
      part[gpos] = vals[s];
  }
}

// Per bucket: compute own base (reduce bktcur[0..b)), stage window in LDS,
// count -> scan -> offsets + dinv, then compact scatter into final CSR slots.
__global__ __launch_bounds__(256) void k_csr3(const int* __restrict__ part,
                                              const int* __restrict__ bktcur,
                                              int* __restrict__ offsets,
                                              int* __restrict__ csr_src,
                                              float* __restrict__ dinv, int n,
                                              int E) {
  __shared__ int win[CAP];  // 48KB window stage
  __shared__ int cnt[256];
  __shared__ int ts[256];
  const int b = blockIdx.x;
  const int node0 = b << BSHIFT;
  const int nn = min(256, n - node0);
  const int t = threadIdx.x;

  // bucket base = sum_{j<b} (bktcur[j] - j*CAP)
  int partial = 0;
  for (int j = t; j < b; j += 256) partial += bktcur[j] - j * CAP;
  ts[t] = partial;
  __syncthreads();
  for (int off = 128; off > 0; off >>= 1) {
    if (t < off) ts[t] += ts[t + off];
    __syncthreads();
  }
  const int w0 = ts[0];
  __syncthreads();

  const int w0p = b * CAP;
  const int wcnt = min(bktcur[b], w0p + CAP) - w0p;
  for (int e = t; e < wcnt; e += 256) win[e] = part[w0p + e];
  cnt[t] = 0;
  __syncthreads();
  for (int e = t; e < wcnt; e += 256)
    atomicAdd(&cnt[win[e] & ((1 << BSHIFT) - 1)], 1);
  __syncthreads();
  const int c = cnt[t];
  ts[t] = c;
  __syncthreads();
  for (int off = 1; off < 256; off <<= 1) {
    const int u = (t >= off) ? ts[t - off] : 0;
    __syncthreads();
    ts[t] += u;
    __syncthreads();
  }
  const int excl = ts[t] - c;
  if (t < nn) {
    offsets[node0 + t] = w0 + excl;
    dinv[node0 + t] = rsqrtf((float)c + 1.0f);
  }
  if (b == 0 && t == 0) offsets[n] = E;
  cnt[t] = w0 + excl;  // becomes cursor
  __syncthreads();
  for (int e = t; e < wcnt; e += 256) {
    const int p = win[e];
    const int pos = atomicAdd(&cnt[p & ((1 << BSHIFT) - 1)], 1);
    csr_src[pos] = p >> BSHIFT;
  }
}

// ---------------------------------------------------------------------------
// MFMA fp16 GEMM: Hout[N,COLS](fp16) = (A[N,128] @ W[128,COLS]) * dinv[row].
// ---------------------------------------------------------------------------
template <typename TA, int COLS>
__global__ __launch_bounds__(256) void k_gemm_mfma(const TA* __restrict__ A,
                                                   const float* __restrict__ W,
                                                   const float* __restrict__ dinv,
                                                   __half* __restrict__ Hout,
                                                   int N, int ntiles) {
  constexpr int RW = (COLS == 128) ? 2 : 4;  // row-waves per tile
  constexpr int RPT = RW * 16;               // rows per tile
  __shared__ _Float16 Wt[128 * COLS];
  __shared__ _Float16 Lb[4][16][72];
  const int tid = threadIdx.x;
  const int w = tid >> 6;
  const int l = tid & 63;

  for (int f = tid; f < (128 * COLS) / 4; f += 256) {
    const int k = f / (COLS / 4);
    const int c4 = (f % (COLS / 4)) * 4;
    const float4 wv = *reinterpret_cast<const float4*>(W + (size_t)k * COLS + c4);
#pragma unroll
    for (int j = 0; j < 4; ++j) {
      const int cc = c4 + j;
      Wt[(cc * 128 + k) ^ ((cc & 7) << 3)] = (_Float16)(&wv.x)[j];
    }
  }
  __syncthreads();

  const int colw = (COLS == 128) ? (w >> 1) * 64 : 0;
  const int rw = (COLS == 128) ? (w & 1) : w;
  const int koff = (l >> 4) * 8;

  half8 bf[4][4];
#pragma unroll
  for (int t = 0; t < 4; ++t)
#pragma unroll
    for (int s = 0; s < 4; ++s) {
      const int cc = colw + 16 * t + (l & 15);
      const int kk = 32 * s + koff;
      bf[t][s] =
          *reinterpret_cast<const half8*>(&Wt[(cc * 128 + kk) ^ ((cc & 7) << 3)]);
    }

  for (int tile = blockIdx.x; tile < ntiles; tile += gridDim.x) {
    const int row = tile * RPT + rw * 16 + (l & 15);
    const int rowc = (row < N) ? row : (N - 1);
    f32x4 acc[4];
#pragma unroll
    for (int t = 0; t < 4; ++t) acc[t] = (f32x4){0.f, 0.f, 0.f, 0.f};

#pragma unroll
    for (int s = 0; s < 4; ++s) {
      half8 af;
      if constexpr (sizeof(TA) == 4) {
        const float* ap = (const float*)A + (size_t)rowc * 128 + 32 * s + koff;
        const float4 a0 = *reinterpret_cast<const float4*>(ap);
        const float4 a1 = *reinterpret_cast<const float4*>(ap + 4);
#pragma unroll
        for (int j = 0; j < 4; ++j) {
          af[j] = (_Float16)(&a0.x)[j];
          af[4 + j] = (_Float16)(&a1.x)[j];
        }
      } else {
        af = *reinterpret_cast<const half8*>((const __half*)A +
                                             (size_t)rowc * 128 + 32 * s + koff);
      }
#pragma unroll
      for (int t = 0; t < 4; ++t)
        acc[t] = __builtin_amdgcn_mfma_f32_16x16x32_f16(af, bf[t][s], acc[t],
                                                        0, 0, 0);
    }

    const int rbase = tile * RPT + rw * 16 + (l >> 4) * 4;
    float dr[4];
#pragma unroll
    for (int r = 0; r < 4; ++r) {
      const int rr = rbase + r;
      dr[r] = (rr < N) ? dinv[rr] : 0.f;
    }

#pragma unroll
    for (int t = 0; t < 4; ++t)
#pragma unroll
      for (int r = 0; r < 4; ++r)
        Lb[w][(l >> 4) * 4 + r][16 * t + (l & 15)] = (_Float16)(acc[t][r] * dr[r]);
    const int orow = tile * RPT + rw * 16 + (l & 15);
    if (orow < N) {
      const int ch = (l >> 4) * 16;
      const half8 v0 = *reinterpret_cast<const half8*>(&Lb[w][l & 15][ch]);
      const half8 v1 = *reinterpret_cast<const half8*>(&Lb[w][l & 15][ch + 8]);
      __half* hp = Hout + (size_t)orow * COLS + colw + ch;
      *reinterpret_cast<half8*>(hp) = v0;
      *reinterpret_cast<half8*>(hp + 8) = v1;
    }
  }
}

// ---------------------------------------------------------------------------
// Wide CSR gather over pre-scaled H (Hs = h*dinv, fp16), fp32 accumulate.
//   out[i] = relu( dinv[i] * (sum Hs[s] + Hs[i]) + bias )
// One wave per node; 8 edge slots x 8 channel-block lanes; 16-deep unrolled
// main loop (no masking), masked 8-tail. Round-15 proven bodies.
// ---------------------------------------------------------------------------
__global__ __launch_bounds__(256) void k_gather128(
    const __half* __restrict__ H, const int* __restrict__ offsets,
    const int* __restrict__ csr_src, const float* __restrict__ dinv,
    const float* __restrict__ bias, __half* __restrict__ out, int N) {
  const int lane = threadIdx.x & 63;
  const int g = lane >> 3;  // 0..7 edge slot
  const int sl = lane & 7;  // 0..7 channel block (16 ch)
  int w = (blockIdx.x * 256 + threadIdx.x) >> 6;
  const int nw = (gridDim.x * 256) >> 6;
  for (int i = w; i < N; i += nw) {
    const int beg = offsets[i];
    const int end = offsets[i + 1];
    float acc[16];
    {
      const float vf = (g == 0) ? 1.f : 0.f;
      const float4 ha = *reinterpret_cast<const float4*>(H + (size_t)i * 128 + sl * 16);
      const float4 hb = *reinterpret_cast<const float4*>(H + (size_t)i * 128 + sl * 16 + 8);
      const __half2* pa = reinterpret_cast<const __half2*>(&ha);
      const __half2* pb = reinterpret_cast<const __half2*>(&hb);
#pragma unroll
      for (int q = 0; q < 4; ++q) {
        const float2 fa = __half22float2(pa[q]);
        const float2 fb = __half22float2(pb[q]);
        acc[q * 2] = vf * fa.x;
        acc[q * 2 + 1] = vf * fa.y;
        acc[8 + q * 2] = vf * fb.x;
        acc[8 + q * 2 + 1] = vf * fb.y;
      }
    }
    int base = beg;
    for (; base + 16 <= end; base += 16) {  // full groups: no masking
      const int s0 = __builtin_nontemporal_load(csr_src + base + g);
      const int s1 = __builtin_nontemporal_load(csr_src + base + 8 + g);
      const float4 h0a = *reinterpret_cast<const float4*>(H + (size_t)s0 * 128 + sl * 16);
      const float4 h0b = *reinterpret_cast<const float4*>(H + (size_t)s0 * 128 + sl * 16 + 8);
      const float4 h1a = *reinterpret_cast<const float4*>(H + (size_t)s1 * 128 + sl * 16);
      const float4 h1b = *reinterpret_cast<const float4*>(H + (size_t)s1 * 128 + sl * 16 + 8);
      const __half2* p0a = reinterpret_cast<const __half2*>(&h0a);
      const __half2* p0b = reinterpret_cast<const __half2*>(&h0b);
      const __half2* p1a = reinterpret_cast<const __half2*>(&h1a);
      const __half2* p1b = reinterpret_cast<const __half2*>(&h1b);
#pragma unroll
      for (int q = 0; q < 4; ++q) {
        const float2 f0a = __half22float2(p0a[q]);
        const float2 f0b = __half22float2(p0b[q]);
        const float2 f1a = __half22float2(p1a[q]);
        const float2 f1b = __half22float2(p1b[q]);
        acc[q * 2] += f0a.x + f1a.x;
        acc[q * 2 + 1] += f0a.y + f1a.y;
        acc[8 + q * 2] += f0b.x + f1b.x;
        acc[8 + q * 2 + 1] += f0b.y + f1b.y;
      }
    }
    for (; base < end; base += 8) {  // masked tail
      const int e = base + g;
      const bool v = e < end;
      const int s = v ? __builtin_nontemporal_load(csr_src + e) : i;
      const float vf = v ? 1.f : 0.f;
      const float4 ha = *reinterpret_cast<const float4*>(H + (size_t)s * 128 + sl * 16);
      const float4 hb = *reinterpret_cast<const float4*>(H + (size_t)s * 128 + sl * 16 + 8);
      const __half2* pa = reinterpret_cast<const __half2*>(&ha);
      const __half2* pb = reinterpret_cast<const __half2*>(&hb);
#pragma unroll
      for (int q = 0; q < 4; ++q) {
        const float2 fa = __half22float2(pa[q]);
        const float2 fb = __half22float2(pb[q]);
        acc[q * 2] = fmaf(vf, fa.x, acc[q * 2]);
        acc[q * 2 + 1] = fmaf(vf, fa.y, acc[q * 2 + 1]);
        acc[8 + q * 2] = fmaf(vf, fb.x, acc[8 + q * 2]);
        acc[8 + q * 2 + 1] = fmaf(vf, fb.y, acc[8 + q * 2 + 1]);
      }
    }
#pragma unroll
    for (int j = 0; j < 16; ++j) {
      float a = acc[j];
      a += __shfl_xor(a, 8);
      a += __shfl_xor(a, 16);
      a += __shfl_xor(a, 32);
      acc[j] = a;
    }
    if (g == 0) {
      const float di = dinv[i];
      __half2 ov[8];
#pragma unroll
      for (int q = 0; q < 8; ++q) {
        const float2 bv = *reinterpret_cast<const float2*>(bias + sl * 16 + q * 2);
        ov[q] = __floats2half2_rn(fmaxf(fmaf(di, acc[q * 2], bv.x), 0.f),
                                  fmaxf(fmaf(di, acc[q * 2 + 1], bv.y), 0.f));
      }
      __half* op = out + (size_t)i * 128 + sl * 16;
      *reinterpret_cast<float4*>(op) = *reinterpret_cast<const float4*>(&ov[0]);
      *reinterpret_cast<float4*>(op + 8) = *reinterpret_cast<const float4*>(&ov[4]);
    }
  }
}

__global__ __launch_bounds__(256) void k_gather64(
    const __half* __restrict__ H, const int* __restrict__ offsets,
    const int* __restrict__ csr_src, const float* __restrict__ dinv,
    const float* __restrict__ bias, float* __restrict__ out, int N) {
  const int lane = threadIdx.x & 63;
  const int g = lane >> 3;  // 0..7 edge slot
  const int sl = lane & 7;  // 0..7 channel block (8 ch)
  int w = (blockIdx.x * 256 + threadIdx.x) >> 6;
  const int nw = (gridDim.x * 256) >> 6;
  for (int i = w; i < N; i += nw) {
    const int beg = offsets[i];
    const int end = offsets[i + 1];
    float acc[8];
    {
      const float vf = (g == 0) ? 1.f : 0.f;
      const float4 ha = *reinterpret_cast<const float4*>(H + (size_t)i * 64 + sl * 8);
      const __half2* pa = reinterpret_cast<const __half2*>(&ha);
#pragma unroll
      for (int q = 0; q < 4; ++q) {
        const float2 fa = __half22float2(pa[q]);
        acc[q * 2] = vf * fa.x;
        acc[q * 2 + 1] = vf * fa.y;
      }
    }
    int base = beg;
    for (; base + 16 <= end; base += 16) {
      const int s0 = __builtin_nontemporal_load(csr_src + base + g);
      const int s1 = __builtin_nontemporal_load(csr_src + base + 8 + g);
      const float4 h0 = *reinterpret_cast<const float4*>(H + (size_t)s0 * 64 + sl * 8);
      const float4 h1 = *reinterpret_cast<const float4*>(H + (size_t)s1 * 64 + sl * 8);
      const __half2* p0 = reinterpret_cast<const __half2*>(&h0);
      const __half2* p1 = reinterpret_cast<const __half2*>(&h1);
#pragma unroll
      for (int q = 0; q < 4; ++q) {
        const float2 f0 = __half22float2(p0[q]);
        const float2 f1 = __half22float2(p1[q]);
        acc[q * 2] += f0.x + f1.x;
        acc[q * 2 + 1] += f0.y + f1.y;
      }
    }
    for (; base < end; base += 8) {
      const int e = base + g;
      const bool v = e < end;
      const int s = v ? __builtin_nontemporal_load(csr_src + e) : i;
      const float vf = v ? 1.f : 0.f;
      const float4 ha = *reinterpret_cast<const float4*>(H + (size_t)s * 64 + sl * 8);
      const __half2* pa = reinterpret_cast<const __half2*>(&ha);
#pragma unroll
      for (int q = 0; q < 4; ++q) {
        const float2 fa = __half22float2(pa[q]);
        acc[q * 2] = fmaf(vf, fa.x, acc[q * 2]);
        acc[q * 2 + 1] = fmaf(vf, fa.y, acc[q * 2 + 1]);
      }
    }
#pragma unroll
    for (int j = 0; j < 8; ++j) {
      float a = acc[j];
      a += __shfl_xor(a, 8);
      a += __shfl_xor(a, 16);
      a += __shfl_xor(a, 32);
      acc[j] = a;
    }
    if (g == 0) {
      const float di = dinv[i];
      float* op = out + (size_t)i * 64 + sl * 8;
      const float4 b0 = *reinterpret_cast<const float4*>(bias + sl * 8);
      const float4 b1 = *reinterpret_cast<const float4*>(bias + sl * 8 + 4);
      float4 o;
      o.x = fmaxf(fmaf(di, acc[0], b0.x), 0.f);
      o.y = fmaxf(fmaf(di, acc[1], b0.y), 0.f);
      o.z = fmaxf(fmaf(di, acc[2], b0.z), 0.f);
      o.w = fmaxf(fmaf(di, acc[3], b0.w), 0.f);
      *reinterpret_cast<float4*>(op) = o;
      o.x = fmaxf(fmaf(di, acc[4], b1.x), 0.f);
      o.y = fmaxf(fmaf(di, acc[5], b1.y), 0.f);
      o.z = fmaxf(fmaf(di, acc[6], b1.z), 0.f);
      o.w = fmaxf(fmaf(di, acc[7], b1.w), 0.f);
      *reinterpret_cast<float4*>(op + 4) = o;
    }
  }
}

extern "C" void kernel_launch(void* const* d_in, const int* in_sizes, int n_in,
                              void* d_out, int out_size, void* d_ws,
                              size_t ws_size, hipStream_t stream) {
  const float* x  = (const float*)d_in[0];
  const int*   ei = (const int*)d_in[1];
  const float* W1 = (const float*)d_in[2];
  const float* b1 = (const float*)d_in[3];
  const float* W2 = (const float*)d_in[4];
  const float* b2 = (const float*)d_in[5];

  const int IN  = 128;
  const int n   = in_sizes[0] / IN;   // 100000
  const int E   = in_sizes[1] / 2;    // 3200000
  const int* srcv = ei;
  const int* dstv = ei + E;
  float* out = (float*)d_out;

  const int NBKT = (n + 255) >> BSHIFT;    // buckets (391)
  const int NCHK = (E + 4095) / 4096;      // partition chunks (782)
  const int NT1  = (n + 31) / 32;          // layer-1 tiles (3125)
  const int NT2  = (n + 63) / 64;          // layer-2 tiles (1563)

  // Workspace (~65 MB): part[] aliases hprime (dead until gather128 writes it).
  char* p = (char*)d_ws;
  auto take = [&](size_t bytes) {
    char* r = p;
    p += (bytes + 255) & ~(size_t)255;
    return r;
  };
  float*  dinv    = (float*)take((size_t)n * 4);
  int*    offsets = (int*)take((size_t)(n + 1) * 4);
  int*    bktcur  = (int*)take(512 * 4);
  int*    csr_src = (int*)take((size_t)E * 4);            // 12.8 MB
  __half* H16     = (__half*)take((size_t)n * 128 * 2);   // 25.6 MB (H1s; later H2s)
  __half* hprime  = (__half*)take((size_t)n * 128 * 2);   // 25.6 MB (h' fp16)
  int*    part    = (int*)hprime;                          // 19.2 MB alias

  // --- single-pass CSR build (3 kernels) ---
  k_binit<<<(NBKT + 255) / 256, 256, 0, stream>>>(bktcur, NBKT);
  k_part3<<<NCHK, 256, 0, stream>>>(srcv, dstv, bktcur, part, E, NBKT);
  k_csr3<<<NBKT, 256, 0, stream>>>(part, bktcur, offsets, csr_src, dinv, n, E);

  // --- layer 1: H1s = (x@W1)*dinv (fp16) ; gather -> h' (fp16) ---
  k_gemm_mfma<float, 128><<<512, 256, 0, stream>>>(x, W1, dinv, H16, n, NT1);
  k_gather128<<<25000, 256, 0, stream>>>(H16, offsets, csr_src, dinv, b1,
                                         hprime, n);

  // --- layer 2: H2s = (h'@W2)*dinv (fp16) ; gather -> d_out ---
  k_gemm_mfma<__half, 64><<<512, 256, 0, stream>>>(hprime, W2, dinv, H16, n, NT2);
  k_gather64<<<25000, 256, 0, stream>>>(H16, offsets, csr_src, dinv, b2,
                                        out, n);
}